// Round 5
// baseline (100.726 us; speedup 1.0000x reference)
//
#include <hip/hip_runtime.h>

#define TT 512
#define DD 256
#define BB 2
#define MM (BB*TT)          // 1024

// v_pk_fma_f32: 2 fp32 FMAs per instruction (VOP3P) — R4 PROVED this
// dual-rates on gfx950 (halved GEMM time).  op_sel broadcasts the A-operand
// scalar: PK_LO uses a.lo in both halves, PK_HI uses a.hi.  Bit-identical
// to the scalar fmaf pair.
#define PK_LO(acc, a, b) \
    asm("v_pk_fma_f32 %0, %1, %2, %0 op_sel:[0,0,0] op_sel_hi:[0,1,1]" \
        : "+v"(acc) : "v"(a), "v"(b))
#define PK_HI(acc, a, b) \
    asm("v_pk_fma_f32 %0, %1, %2, %0 op_sel:[1,0,0] op_sel_hi:[1,1,1]" \
        : "+v"(acc) : "v"(a), "v"(b))

// ---------------------------------------------------------------------------
// K1: k/v/r = timemix(X) @ W^T, stored TRANSPOSED as (B, D, T).
// 768 blocks x 4 waves, wave-private K-quarter, no-barrier main loop,
// v_pk_fma_f32 micro-kernel (R8).  R9: inner reads as explicit b128.
// NOTE (R4 post-mortem): do NOT fuse stages with grid barriers — agent-scope
// fences cost ~50-70us on MI355X.
// ---------------------------------------------------------------------------
__global__ __launch_bounds__(256)
void gemm_mix_t(const float* __restrict__ X, const float* __restrict__ Xlast,
                const float* __restrict__ W0, const float* __restrict__ W1,
                const float* __restrict__ W2,
                const float* __restrict__ mx0, const float* __restrict__ mx1,
                const float* __restrict__ mx2,
                float* __restrict__ O0, float* __restrict__ O1,
                float* __restrict__ O2)
{
    const int mat = blockIdx.z;
    const float* W  = (mat == 0) ? W0  : (mat == 1) ? W1  : W2;
    const float* mx = (mat == 0) ? mx0 : (mat == 1) ? mx1 : mx2;
    float*       O  = (mat == 0) ? O0  : (mat == 1) ? O1  : O2;

    const int n0   = blockIdx.x * 32;
    const int m0   = blockIdx.y * 32;
    const int b    = m0 / TT;
    const int t0   = m0 % TT;
    const int tid  = threadIdx.x;
    const int wv   = tid >> 6;       // 0..3: K-quarter owner
    const int lane = tid & 63;

    const int cc = (lane & 7) * 4;   // k offset within 32-chunk (staging)
    const int g  = lane >> 3;        // 0..7 row group (staging)
    const int tm = lane >> 3;        // 0..7 (m groups of 4, compute)
    const int tn = lane & 7;         // 0..7 (n groups of 4, compute)

    __shared__ float As[4][32][36];  // [wave][k][m] pad 36
    __shared__ float Bs[4][32][36];  // [wave][k][n]

    const int kb = wv * 64;

    float4 a[4], w4[4];              // prefetch regs (mix already applied)
    auto load_chunk = [&](int k0) {
        const float4 mv = *(const float4*)&mx[k0 + cc];
        #pragma unroll
        for (int i = 0; i < 4; ++i) {
            const int rr  = g + 8 * i;
            const int row = m0 + rr;
            const float4 xc = *(const float4*)&X[(size_t)row * DD + k0 + cc];
            float4 xp;
            if (t0 + rr == 0) xp = *(const float4*)&Xlast[b * DD + k0 + cc];
            else              xp = *(const float4*)&X[(size_t)(row - 1) * DD + k0 + cc];
            a[i].x = xp.x + (xc.x - xp.x) * mv.x;
            a[i].y = xp.y + (xc.y - xp.y) * mv.y;
            a[i].z = xp.z + (xc.z - xp.z) * mv.z;
            a[i].w = xp.w + (xc.w - xp.w) * mv.w;
            w4[i] = *(const float4*)&W[(size_t)(n0 + rr) * DD + k0 + cc];
        }
    };

    float2 acc2[4][2] = {};          // [i][jp]: (acc[i][2jp], acc[i][2jp+1])
    load_chunk(kb);

    #pragma unroll
    for (int c = 0; c < 2; ++c) {
        #pragma unroll
        for (int i = 0; i < 4; ++i) {
            const int rr = g + 8 * i;
            As[wv][cc + 0][rr] = a[i].x; As[wv][cc + 1][rr] = a[i].y;
            As[wv][cc + 2][rr] = a[i].z; As[wv][cc + 3][rr] = a[i].w;
            Bs[wv][cc + 0][rr] = w4[i].x; Bs[wv][cc + 1][rr] = w4[i].y;
            Bs[wv][cc + 2][rr] = w4[i].z; Bs[wv][cc + 3][rr] = w4[i].w;
        }
        if (c == 0) load_chunk(kb + 32);
        // no barrier: wave-private buffer, program order covers LDS deps
        #pragma unroll
        for (int kk = 0; kk < 32; ++kk) {
            const float4 a4 = *(const float4*)&As[wv][kk][tm * 4];
            const float4 b4 = *(const float4*)&Bs[wv][kk][tn * 4];
            const float2 a01 = make_float2(a4.x, a4.y);
            const float2 a23 = make_float2(a4.z, a4.w);
            const float2 b01 = make_float2(b4.x, b4.y);
            const float2 b23 = make_float2(b4.z, b4.w);
            PK_LO(acc2[0][0], a01, b01); PK_LO(acc2[0][1], a01, b23);
            PK_HI(acc2[1][0], a01, b01); PK_HI(acc2[1][1], a01, b23);
            PK_LO(acc2[2][0], a23, b01); PK_LO(acc2[2][1], a23, b23);
            PK_HI(acc2[3][0], a23, b01); PK_HI(acc2[3][1], a23, b23);
        }
    }

    // cross-wave K reduction: waves 1..3 park accs in their (dead) A buffers
    if (wv != 0) {
        float* park = &As[wv][0][0];            // 1152 floats >= 1024
        #pragma unroll
        for (int i = 0; i < 4; ++i)
            *(float4*)&park[(i * 64 + lane) * 4] =
                make_float4(acc2[i][0].x, acc2[i][0].y, acc2[i][1].x, acc2[i][1].y);
    }
    __syncthreads();
    if (wv == 0) {
        #pragma unroll
        for (int w = 1; w < 4; ++w) {
            const float* park = &As[w][0][0];
            #pragma unroll
            for (int i = 0; i < 4; ++i) {
                const float4 o = *(const float4*)&park[(i * 64 + lane) * 4];
                acc2[i][0].x += o.x; acc2[i][0].y += o.y;
                acc2[i][1].x += o.z; acc2[i][1].y += o.w;
            }
        }
        // store transposed: O[(b, n, t)] ; t = t0+tm*4+i, n = n0+tn*4+j
        const float4 oj0 = make_float4(acc2[0][0].x, acc2[1][0].x, acc2[2][0].x, acc2[3][0].x);
        const float4 oj1 = make_float4(acc2[0][0].y, acc2[1][0].y, acc2[2][0].y, acc2[3][0].y);
        const float4 oj2 = make_float4(acc2[0][1].x, acc2[1][1].x, acc2[2][1].x, acc2[3][1].x);
        const float4 oj3 = make_float4(acc2[0][1].y, acc2[1][1].y, acc2[2][1].y, acc2[3][1].y);
        *(float4*)&O[(size_t)(b * DD + n0 + tn * 4 + 0) * TT + t0 + tm * 4] = oj0;
        *(float4*)&O[(size_t)(b * DD + n0 + tn * 4 + 1) * TT + t0 + tm * 4] = oj1;
        *(float4*)&O[(size_t)(b * DD + n0 + tn * 4 + 2) * TT + t0 + tm * 4] = oj2;
        *(float4*)&O[(size_t)(b * DD + n0 + tn * 4 + 3) * TT + t0 + tm * 4] = oj3;
    }
}

// ---------------------------------------------------------------------------
// K2: WKV parallel scan.  R9: channel split across 4 waves (L=2/lane,
// quarter-T per wave); 256 blocks x 512 thr = 8 waves/block = 2 waves/SIMD
// on every CU (was 1/SIMD -> fully exposed load latency).  Segment affine
// maps composed through a 24-float LDS handoff + one barrier.
// ---------------------------------------------------------------------------
__global__ __launch_bounds__(512)
void wkv_scan(const float* __restrict__ kT, const float* __restrict__ vT,
              const float* __restrict__ rT, const float* __restrict__ x,
              const float* __restrict__ last_num, const float* __restrict__ last_den,
              const float* __restrict__ time_decay, const float* __restrict__ time_first,
              float* __restrict__ yT, float* __restrict__ out)
{
    const int tid  = threadIdx.x;
    const int chl  = tid >> 8;           // 0..1 channel within block
    const int q    = (tid >> 6) & 3;     // 0..3 T-quarter owner
    const int lane = tid & 63;
    const int ch   = blockIdx.x * 2 + chl;
    const int b    = ch >> 8;
    const int d    = ch & (DD - 1);

    const float w  = -__expf(time_decay[d]);
    const float ew = __expf(w);
    const float eu = __expf(time_first[d]);

    const size_t base = (size_t)ch * TT + q * (TT / 4) + lane * 2;
    const float2 k2 = *(const float2*)(kT + base);
    const float2 v2 = *(const float2*)(vT + base);
    const float2 r2 = *(const float2*)(rT + base);
    const float k_[2] = {k2.x, k2.y};
    const float v_[2] = {v2.x, v2.y};
    const float r_[2] = {r2.x, r2.y};

    float ek[2], ekv[2], sr[2];
    #pragma unroll
    for (int i = 0; i < 2; ++i) {
        ek[i]  = __expf(k_[i]);
        ekv[i] = ek[i] * v_[i];
        sr[i]  = __builtin_amdgcn_rcpf(1.0f + __expf(-r_[i]));
    }

    float A = __expf(w * 2.0f);
    float Bn = 0.0f, Bd = 0.0f;
    #pragma unroll
    for (int i = 0; i < 2; ++i) {
        Bn = fmaf(ew, Bn, ekv[i]);
        Bd = fmaf(ew, Bd, ek[i]);
    }

    #pragma unroll
    for (int s = 1; s < 64; s <<= 1) {
        const float Ax  = __shfl_up(A, s, 64);
        const float Bnx = __shfl_up(Bn, s, 64);
        const float Bdx = __shfl_up(Bd, s, 64);
        if (lane >= s) {
            Bn = fmaf(A, Bnx, Bn);
            Bd = fmaf(A, Bdx, Bd);
            A *= Ax;
        }
    }

    // publish each quarter's inclusive total for downstream quarters
    __shared__ float h[2][4][3];
    if (lane == 63) { h[chl][q][0] = A; h[chl][q][1] = Bn; h[chl][q][2] = Bd; }

    float Aex  = __shfl_up(A, 1, 64);
    float Bnex = __shfl_up(Bn, 1, 64);
    float Bdex = __shfl_up(Bd, 1, 64);
    if (lane == 0) { Aex = 1.0f; Bnex = 0.0f; Bdex = 0.0f; }

    __syncthreads();

    // compose quarters 0..q-1 onto the incoming state (order matters)
    float s0n = last_num[ch], s0d = last_den[ch];
    for (int j = 0; j < q; ++j) {
        s0n = fmaf(h[chl][j][0], s0n, h[chl][j][1]);
        s0d = fmaf(h[chl][j][0], s0d, h[chl][j][2]);
    }
    float sn = fmaf(Aex, s0n, Bnex);
    float sd = fmaf(Aex, s0d, Bdex);

    float y_[2];
    #pragma unroll
    for (int i = 0; i < 2; ++i) {
        const float euk = eu * ek[i];
        const float wkv = (sn + eu * ekv[i]) * __builtin_amdgcn_rcpf(sd + euk);
        y_[i] = wkv * sr[i];
        sn = fmaf(ew, sn, ekv[i]);
        sd = fmaf(ew, sd, ek[i]);
    }
    *(float2*)(yT + base) = make_float2(y_[0], y_[1]);

    if (q == 3 && lane == 63) {
        out[MM * DD + BB * DD + ch]     = sn;
        out[MM * DD + 2 * BB * DD + ch] = sd;
    }
    if (q == 0 && lane == 0)
        out[MM * DD + ch] = x[(b * TT + TT - 1) * DD + d];
}

// ---------------------------------------------------------------------------
// K3: out = yT^T @ Wo^T.  4-way K-split, wave-private dbuf, no main-loop
// barrier, pk_fma micro-kernel.  R9: explicit b128 inner reads.
// ---------------------------------------------------------------------------
__global__ __launch_bounds__(256)
void gemm_out(const float* __restrict__ yT, const float* __restrict__ Wo,
              float* __restrict__ O)
{
    const int n0   = blockIdx.x * 32;
    const int m0   = blockIdx.y * 32;
    const int b    = m0 >> 9;           // /TT
    const int t0   = m0 & (TT - 1);
    const int tid  = threadIdx.x;
    const int wv   = tid >> 6;          // 0..3: K-quarter owner
    const int lane = tid & 63;

    __shared__ float As[4][2][32][40];  // [wave][buf][k][t] pad 40
    __shared__ float Bs[4][2][32][36];  // [wave][buf][k][n] pad 36

    const int tm = lane >> 3;           // 0..7
    const int tn = lane & 7;            // 0..7
    const int kr = lane >> 3;           // A stage: k row group
    const int mq = (lane & 7) * 4;      // A stage: t
    const int cc = (lane & 7) * 4;      // B stage: k
    const int g  = lane >> 3;           // B stage: n row group

    const int kb = wv * 64;

    float4 av[4], wv4[4];
    auto load_chunk = [&](int k0) {
        #pragma unroll
        for (int i = 0; i < 4; ++i)
            av[i] = *(const float4*)&yT[(size_t)(b * DD + k0 + kr + 8 * i) * TT + t0 + mq];
        #pragma unroll
        for (int i = 0; i < 4; ++i)
            wv4[i] = *(const float4*)&Wo[(size_t)(n0 + g + 8 * i) * DD + k0 + cc];
    };

    float2 acc2[4][2] = {};
    load_chunk(kb);

    #pragma unroll
    for (int c = 0; c < 2; ++c) {
        const int buf = c & 1;
        #pragma unroll
        for (int i = 0; i < 4; ++i)
            *(float4*)&As[wv][buf][kr + 8 * i][mq] = av[i];
        #pragma unroll
        for (int i = 0; i < 4; ++i) {
            const int rr = g + 8 * i;
            Bs[wv][buf][cc + 0][rr] = wv4[i].x; Bs[wv][buf][cc + 1][rr] = wv4[i].y;
            Bs[wv][buf][cc + 2][rr] = wv4[i].z; Bs[wv][buf][cc + 3][rr] = wv4[i].w;
        }
        if (c == 0) load_chunk(kb + 32);
        // no barrier: wave-private
        #pragma unroll
        for (int kk = 0; kk < 32; ++kk) {
            const float4 a4 = *(const float4*)&As[wv][buf][kk][tm * 4];
            const float4 b4 = *(const float4*)&Bs[wv][buf][kk][tn * 4];
            const float2 a01 = make_float2(a4.x, a4.y);
            const float2 a23 = make_float2(a4.z, a4.w);
            const float2 b01 = make_float2(b4.x, b4.y);
            const float2 b23 = make_float2(b4.z, b4.w);
            PK_LO(acc2[0][0], a01, b01); PK_LO(acc2[0][1], a01, b23);
            PK_HI(acc2[1][0], a01, b01); PK_HI(acc2[1][1], a01, b23);
            PK_LO(acc2[2][0], a23, b01); PK_LO(acc2[2][1], a23, b23);
            PK_HI(acc2[3][0], a23, b01); PK_HI(acc2[3][1], a23, b23);
        }
    }

    // cross-wave K reduction: waves 1..3 park accs (stride 20 -> conflict-free)
    if (wv != 0) {
        float* park = &As[wv][0][0][0];         // 2560 floats >= 64*20
        #pragma unroll
        for (int i = 0; i < 4; ++i)
            *(float4*)&park[lane * 20 + i * 4] =
                make_float4(acc2[i][0].x, acc2[i][0].y, acc2[i][1].x, acc2[i][1].y);
    }
    __syncthreads();
    if (wv == 0) {
        #pragma unroll
        for (int w = 1; w < 4; ++w) {
            const float* park = &As[w][0][0][0];
            #pragma unroll
            for (int i = 0; i < 4; ++i) {
                const float4 o = *(const float4*)&park[lane * 20 + i * 4];
                acc2[i][0].x += o.x; acc2[i][0].y += o.y;
                acc2[i][1].x += o.z; acc2[i][1].y += o.w;
            }
        }
        #pragma unroll
        for (int i = 0; i < 4; ++i)
            *(float4*)&O[(size_t)(m0 + tm * 4 + i) * DD + n0 + tn * 4] =
                make_float4(acc2[i][0].x, acc2[i][0].y, acc2[i][1].x, acc2[i][1].y);
    }
}

// ---------------------------------------------------------------------------
extern "C" void kernel_launch(void* const* d_in, const int* in_sizes, int n_in,
                              void* d_out, int out_size, void* d_ws, size_t ws_size,
                              hipStream_t stream)
{
    const float* x    = (const float*)d_in[0];
    const float* lx   = (const float*)d_in[1];
    const float* lnum = (const float*)d_in[2];
    const float* lden = (const float*)d_in[3];
    const float* td   = (const float*)d_in[4];
    const float* tf   = (const float*)d_in[5];
    const float* mk   = (const float*)d_in[6];
    const float* mv   = (const float*)d_in[7];
    const float* mr   = (const float*)d_in[8];
    const float* Wk   = (const float*)d_in[9];
    const float* Wv   = (const float*)d_in[10];
    const float* Wr   = (const float*)d_in[11];
    const float* Wo   = (const float*)d_in[12];
    float* out = (float*)d_out;

    float* kT = (float*)d_ws;          // (B, D, T)
    float* vT = kT + MM * DD;
    float* rT = vT + MM * DD;          // raw r (sigmoid applied in K2)
    float* yT = rT + MM * DD;          // (B, D, T) = wkv * sigmoid(r)

    gemm_mix_t<<<dim3(8, 32, 3), 256, 0, stream>>>(
        x, lx, Wk, Wv, Wr, mk, mv, mr, kT, vT, rT);

    wkv_scan<<<dim3(256), 512, 0, stream>>>(
        kT, vT, rT, x, lnum, lden, td, tf, yT, out);

    gemm_out<<<dim3(8, 32), 256, 0, stream>>>(yT, Wo, out);
}

// Round 7
// 97.503 us; speedup vs baseline: 1.0331x; 1.0331x over previous
//
#include <hip/hip_runtime.h>

#define TT 512
#define DD 256
#define BB 2
#define MM (BB*TT)          // 1024

// v_pk_fma_f32: 2 fp32 FMAs per instruction (VOP3P) — R4 PROVED this
// dual-rates on gfx950 (halved GEMM time).  op_sel broadcasts the A-operand
// scalar: PK_LO uses a.lo in both halves, PK_HI uses a.hi.  Bit-identical
// to the scalar fmaf pair.
// R5 post-mortem: feed these from ds_read_b64 pairs (float2 LDS reads), NOT
// repacked float4 components — the repack cost ~1-2us across the GEMMs.
#define PK_LO(acc, a, b) \
    asm("v_pk_fma_f32 %0, %1, %2, %0 op_sel:[0,0,0] op_sel_hi:[0,1,1]" \
        : "+v"(acc) : "v"(a), "v"(b))
#define PK_HI(acc, a, b) \
    asm("v_pk_fma_f32 %0, %1, %2, %0 op_sel:[1,0,0] op_sel_hi:[1,1,1]" \
        : "+v"(acc) : "v"(a), "v"(b))

// ---------------------------------------------------------------------------
// K1: k/v/r = timemix(X) @ W^T, stored TRANSPOSED as (B, D, T).
// 768 blocks x 4 waves, wave-private K-quarter, no-barrier main loop,
// v_pk_fma_f32 micro-kernel.  (R5's K2 4-way split + b128 repack REVERTED:
// +4.2us regression vs this exact structure's 96.57us.)
// NOTE (R4 post-mortem): do NOT fuse stages with grid barriers — agent-scope
// fences cost ~50-70us on MI355X.
// ---------------------------------------------------------------------------
__global__ __launch_bounds__(256)
void gemm_mix_t(const float* __restrict__ X, const float* __restrict__ Xlast,
                const float* __restrict__ W0, const float* __restrict__ W1,
                const float* __restrict__ W2,
                const float* __restrict__ mx0, const float* __restrict__ mx1,
                const float* __restrict__ mx2,
                float* __restrict__ O0, float* __restrict__ O1,
                float* __restrict__ O2)
{
    const int mat = blockIdx.z;
    const float* W  = (mat == 0) ? W0  : (mat == 1) ? W1  : W2;
    const float* mx = (mat == 0) ? mx0 : (mat == 1) ? mx1 : mx2;
    float*       O  = (mat == 0) ? O0  : (mat == 1) ? O1  : O2;

    const int n0   = blockIdx.x * 32;
    const int m0   = blockIdx.y * 32;
    const int b    = m0 / TT;
    const int t0   = m0 % TT;
    const int tid  = threadIdx.x;
    const int wv   = tid >> 6;       // 0..3: K-quarter owner
    const int lane = tid & 63;

    const int cc = (lane & 7) * 4;   // k offset within 32-chunk (staging)
    const int g  = lane >> 3;        // 0..7 row group (staging)
    const int tm = lane >> 3;        // 0..7 (m groups of 4, compute)
    const int tn = lane & 7;         // 0..7 (n groups of 4, compute)

    __shared__ float As[4][32][36];  // [wave][k][m] pad 36
    __shared__ float Bs[4][32][36];  // [wave][k][n]

    const int kb = wv * 64;

    float4 a[4], w4[4];              // prefetch regs (mix already applied)
    auto load_chunk = [&](int k0) {
        const float4 mv = *(const float4*)&mx[k0 + cc];
        #pragma unroll
        for (int i = 0; i < 4; ++i) {
            const int rr  = g + 8 * i;
            const int row = m0 + rr;
            const float4 xc = *(const float4*)&X[(size_t)row * DD + k0 + cc];
            float4 xp;
            if (t0 + rr == 0) xp = *(const float4*)&Xlast[b * DD + k0 + cc];
            else              xp = *(const float4*)&X[(size_t)(row - 1) * DD + k0 + cc];
            a[i].x = xp.x + (xc.x - xp.x) * mv.x;
            a[i].y = xp.y + (xc.y - xp.y) * mv.y;
            a[i].z = xp.z + (xc.z - xp.z) * mv.z;
            a[i].w = xp.w + (xc.w - xp.w) * mv.w;
            w4[i] = *(const float4*)&W[(size_t)(n0 + rr) * DD + k0 + cc];
        }
    };

    float2 acc2[4][2] = {};          // [i][jp]: (acc[i][2jp], acc[i][2jp+1])
    load_chunk(kb);

    #pragma unroll
    for (int c = 0; c < 2; ++c) {
        #pragma unroll
        for (int i = 0; i < 4; ++i) {
            const int rr = g + 8 * i;
            As[wv][cc + 0][rr] = a[i].x; As[wv][cc + 1][rr] = a[i].y;
            As[wv][cc + 2][rr] = a[i].z; As[wv][cc + 3][rr] = a[i].w;
            Bs[wv][cc + 0][rr] = w4[i].x; Bs[wv][cc + 1][rr] = w4[i].y;
            Bs[wv][cc + 2][rr] = w4[i].z; Bs[wv][cc + 3][rr] = w4[i].w;
        }
        if (c == 0) load_chunk(kb + 32);
        // no barrier: wave-private buffer, program order covers LDS deps
        #pragma unroll
        for (int kk = 0; kk < 32; ++kk) {
            const float2 a01 = *(const float2*)&As[wv][kk][tm * 4];
            const float2 a23 = *(const float2*)&As[wv][kk][tm * 4 + 2];
            const float2 b01 = *(const float2*)&Bs[wv][kk][tn * 4];
            const float2 b23 = *(const float2*)&Bs[wv][kk][tn * 4 + 2];
            PK_LO(acc2[0][0], a01, b01); PK_LO(acc2[0][1], a01, b23);
            PK_HI(acc2[1][0], a01, b01); PK_HI(acc2[1][1], a01, b23);
            PK_LO(acc2[2][0], a23, b01); PK_LO(acc2[2][1], a23, b23);
            PK_HI(acc2[3][0], a23, b01); PK_HI(acc2[3][1], a23, b23);
        }
    }

    // cross-wave K reduction: waves 1..3 park accs in their (dead) A buffers
    if (wv != 0) {
        float* park = &As[wv][0][0];            // 1152 floats >= 1024
        #pragma unroll
        for (int i = 0; i < 4; ++i)
            *(float4*)&park[(i * 64 + lane) * 4] =
                make_float4(acc2[i][0].x, acc2[i][0].y, acc2[i][1].x, acc2[i][1].y);
    }
    __syncthreads();
    if (wv == 0) {
        #pragma unroll
        for (int w = 1; w < 4; ++w) {
            const float* park = &As[w][0][0];
            #pragma unroll
            for (int i = 0; i < 4; ++i) {
                const float4 o = *(const float4*)&park[(i * 64 + lane) * 4];
                acc2[i][0].x += o.x; acc2[i][0].y += o.y;
                acc2[i][1].x += o.z; acc2[i][1].y += o.w;
            }
        }
        // store transposed: O[(b, n, t)] ; t = t0+tm*4+i, n = n0+tn*4+j
        const float4 oj0 = make_float4(acc2[0][0].x, acc2[1][0].x, acc2[2][0].x, acc2[3][0].x);
        const float4 oj1 = make_float4(acc2[0][0].y, acc2[1][0].y, acc2[2][0].y, acc2[3][0].y);
        const float4 oj2 = make_float4(acc2[0][1].x, acc2[1][1].x, acc2[2][1].x, acc2[3][1].x);
        const float4 oj3 = make_float4(acc2[0][1].y, acc2[1][1].y, acc2[2][1].y, acc2[3][1].y);
        *(float4*)&O[(size_t)(b * DD + n0 + tn * 4 + 0) * TT + t0 + tm * 4] = oj0;
        *(float4*)&O[(size_t)(b * DD + n0 + tn * 4 + 1) * TT + t0 + tm * 4] = oj1;
        *(float4*)&O[(size_t)(b * DD + n0 + tn * 4 + 2) * TT + t0 + tm * 4] = oj2;
        *(float4*)&O[(size_t)(b * DD + n0 + tn * 4 + 3) * TT + t0 + tm * 4] = oj3;
    }
}

// ---------------------------------------------------------------------------
// K2: WKV parallel scan.  Channel split across 2 waves (L=4, half-T per
// wave); wave1 composes wave0's segment total via a 3-float LDS handoff +
// one barrier.  256 blocks x 256 thr = 4 waves on all 4 SIMDs of every CU.
// (R5's 4-way/512-thr variant with float2 loads REVERTED — regressed.)
// ---------------------------------------------------------------------------
__global__ __launch_bounds__(256)
void wkv_scan(const float* __restrict__ kT, const float* __restrict__ vT,
              const float* __restrict__ rT, const float* __restrict__ x,
              const float* __restrict__ last_num, const float* __restrict__ last_den,
              const float* __restrict__ time_decay, const float* __restrict__ time_first,
              float* __restrict__ yT, float* __restrict__ out)
{
    const int tid  = threadIdx.x;
    const int chl  = tid >> 7;           // 0..1 channel within block
    const int half = (tid >> 6) & 1;     // 0..1 T-half owner
    const int lane = tid & 63;
    const int ch   = blockIdx.x * 2 + chl;
    const int b    = ch >> 8;
    const int d    = ch & (DD - 1);

    const float w  = -__expf(time_decay[d]);
    const float ew = __expf(w);
    const float eu = __expf(time_first[d]);

    const size_t base = (size_t)ch * TT + half * (TT / 2) + lane * 4;
    const float4 k4 = *(const float4*)(kT + base);
    const float4 v4 = *(const float4*)(vT + base);
    const float4 r4 = *(const float4*)(rT + base);
    const float k_[4] = {k4.x, k4.y, k4.z, k4.w};
    const float v_[4] = {v4.x, v4.y, v4.z, v4.w};
    const float r_[4] = {r4.x, r4.y, r4.z, r4.w};

    float ek[4], ekv[4], sr[4];
    #pragma unroll
    for (int i = 0; i < 4; ++i) {
        ek[i]  = __expf(k_[i]);
        ekv[i] = ek[i] * v_[i];
        sr[i]  = __builtin_amdgcn_rcpf(1.0f + __expf(-r_[i]));
    }

    float A = __expf(w * 4.0f);
    float Bn = 0.0f, Bd = 0.0f;
    #pragma unroll
    for (int i = 0; i < 4; ++i) {
        Bn = fmaf(ew, Bn, ekv[i]);
        Bd = fmaf(ew, Bd, ek[i]);
    }

    #pragma unroll
    for (int s = 1; s < 64; s <<= 1) {
        const float Ax  = __shfl_up(A, s, 64);
        const float Bnx = __shfl_up(Bn, s, 64);
        const float Bdx = __shfl_up(Bd, s, 64);
        if (lane >= s) {
            Bn = fmaf(A, Bnx, Bn);
            Bd = fmaf(A, Bdx, Bd);
            A *= Ax;
        }
    }

    // publish wave0's half-total (inclusive at lane 63) for wave1
    __shared__ float h[2][3];
    if (half == 0 && lane == 63) { h[chl][0] = A; h[chl][1] = Bn; h[chl][2] = Bd; }

    float Aex  = __shfl_up(A, 1, 64);
    float Bnex = __shfl_up(Bn, 1, 64);
    float Bdex = __shfl_up(Bd, 1, 64);
    if (lane == 0) { Aex = 1.0f; Bnex = 0.0f; Bdex = 0.0f; }

    __syncthreads();

    float s0n = last_num[ch], s0d = last_den[ch];
    if (half == 1) {
        s0n = fmaf(h[chl][0], s0n, h[chl][1]);
        s0d = fmaf(h[chl][0], s0d, h[chl][2]);
    }
    float sn = fmaf(Aex, s0n, Bnex);
    float sd = fmaf(Aex, s0d, Bdex);

    float y_[4];
    #pragma unroll
    for (int i = 0; i < 4; ++i) {
        const float euk = eu * ek[i];
        const float wkv = (sn + eu * ekv[i]) * __builtin_amdgcn_rcpf(sd + euk);
        y_[i] = wkv * sr[i];
        sn = fmaf(ew, sn, ekv[i]);
        sd = fmaf(ew, sd, ek[i]);
    }
    *(float4*)(yT + base) = make_float4(y_[0], y_[1], y_[2], y_[3]);

    if (half == 1 && lane == 63) {
        out[MM * DD + BB * DD + ch]     = sn;
        out[MM * DD + 2 * BB * DD + ch] = sd;
    }
    if (half == 0 && lane == 0)
        out[MM * DD + ch] = x[(b * TT + TT - 1) * DD + d];
}

// ---------------------------------------------------------------------------
// K3: out = yT^T @ Wo^T.  4-way K-split, wave-private dbuf, no main-loop
// barrier, pk_fma micro-kernel fed by ds_read_b64 pairs.
// ---------------------------------------------------------------------------
__global__ __launch_bounds__(256)
void gemm_out(const float* __restrict__ yT, const float* __restrict__ Wo,
              float* __restrict__ O)
{
    const int n0   = blockIdx.x * 32;
    const int m0   = blockIdx.y * 32;
    const int b    = m0 >> 9;           // /TT
    const int t0   = m0 & (TT - 1);
    const int tid  = threadIdx.x;
    const int wv   = tid >> 6;          // 0..3: K-quarter owner
    const int lane = tid & 63;

    __shared__ float As[4][2][32][40];  // [wave][buf][k][t] pad 40
    __shared__ float Bs[4][2][32][36];  // [wave][buf][k][n] pad 36

    const int tm = lane >> 3;           // 0..7
    const int tn = lane & 7;            // 0..7
    const int kr = lane >> 3;           // A stage: k row group
    const int mq = (lane & 7) * 4;      // A stage: t
    const int cc = (lane & 7) * 4;      // B stage: k
    const int g  = lane >> 3;           // B stage: n row group

    const int kb = wv * 64;

    float4 av[4], wv4[4];
    auto load_chunk = [&](int k0) {
        #pragma unroll
        for (int i = 0; i < 4; ++i)
            av[i] = *(const float4*)&yT[(size_t)(b * DD + k0 + kr + 8 * i) * TT + t0 + mq];
        #pragma unroll
        for (int i = 0; i < 4; ++i)
            wv4[i] = *(const float4*)&Wo[(size_t)(n0 + g + 8 * i) * DD + k0 + cc];
    };

    float2 acc2[4][2] = {};
    load_chunk(kb);

    #pragma unroll
    for (int c = 0; c < 2; ++c) {
        const int buf = c & 1;
        #pragma unroll
        for (int i = 0; i < 4; ++i)
            *(float4*)&As[wv][buf][kr + 8 * i][mq] = av[i];
        #pragma unroll
        for (int i = 0; i < 4; ++i) {
            const int rr = g + 8 * i;
            Bs[wv][buf][cc + 0][rr] = wv4[i].x; Bs[wv][buf][cc + 1][rr] = wv4[i].y;
            Bs[wv][buf][cc + 2][rr] = wv4[i].z; Bs[wv][buf][cc + 3][rr] = wv4[i].w;
        }
        if (c == 0) load_chunk(kb + 32);
        // no barrier: wave-private
        #pragma unroll
        for (int kk = 0; kk < 32; ++kk) {
            const float2 a01 = *(const float2*)&As[wv][buf][kk][tm * 4];
            const float2 a23 = *(const float2*)&As[wv][buf][kk][tm * 4 + 2];
            const float2 b01 = *(const float2*)&Bs[wv][buf][kk][tn * 4];
            const float2 b23 = *(const float2*)&Bs[wv][buf][kk][tn * 4 + 2];
            PK_LO(acc2[0][0], a01, b01); PK_LO(acc2[0][1], a01, b23);
            PK_HI(acc2[1][0], a01, b01); PK_HI(acc2[1][1], a01, b23);
            PK_LO(acc2[2][0], a23, b01); PK_LO(acc2[2][1], a23, b23);
            PK_HI(acc2[3][0], a23, b01); PK_HI(acc2[3][1], a23, b23);
        }
    }

    // cross-wave K reduction: waves 1..3 park accs (stride 20 -> conflict-free)
    if (wv != 0) {
        float* park = &As[wv][0][0][0];         // 2560 floats >= 64*20
        #pragma unroll
        for (int i = 0; i < 4; ++i)
            *(float4*)&park[lane * 20 + i * 4] =
                make_float4(acc2[i][0].x, acc2[i][0].y, acc2[i][1].x, acc2[i][1].y);
    }
    __syncthreads();
    if (wv == 0) {
        #pragma unroll
        for (int w = 1; w < 4; ++w) {
            const float* park = &As[w][0][0][0];
            #pragma unroll
            for (int i = 0; i < 4; ++i) {
                const float4 o = *(const float4*)&park[lane * 20 + i * 4];
                acc2[i][0].x += o.x; acc2[i][0].y += o.y;
                acc2[i][1].x += o.z; acc2[i][1].y += o.w;
            }
        }
        #pragma unroll
        for (int i = 0; i < 4; ++i)
            *(float4*)&O[(size_t)(m0 + tm * 4 + i) * DD + n0 + tn * 4] =
                make_float4(acc2[i][0].x, acc2[i][0].y, acc2[i][1].x, acc2[i][1].y);
    }
}

// ---------------------------------------------------------------------------
extern "C" void kernel_launch(void* const* d_in, const int* in_sizes, int n_in,
                              void* d_out, int out_size, void* d_ws, size_t ws_size,
                              hipStream_t stream)
{
    const float* x    = (const float*)d_in[0];
    const float* lx   = (const float*)d_in[1];
    const float* lnum = (const float*)d_in[2];
    const float* lden = (const float*)d_in[3];
    const float* td   = (const float*)d_in[4];
    const float* tf   = (const float*)d_in[5];
    const float* mk   = (const float*)d_in[6];
    const float* mv   = (const float*)d_in[7];
    const float* mr   = (const float*)d_in[8];
    const float* Wk   = (const float*)d_in[9];
    const float* Wv   = (const float*)d_in[10];
    const float* Wr   = (const float*)d_in[11];
    const float* Wo   = (const float*)d_in[12];
    float* out = (float*)d_out;

    float* kT = (float*)d_ws;          // (B, D, T)
    float* vT = kT + MM * DD;
    float* rT = vT + MM * DD;          // raw r (sigmoid applied in K2)
    float* yT = rT + MM * DD;          // (B, D, T) = wkv * sigmoid(r)

    gemm_mix_t<<<dim3(8, 32, 3), 256, 0, stream>>>(
        x, lx, Wk, Wv, Wr, mk, mv, mr, kT, vT, rT);

    wkv_scan<<<dim3(256), 256, 0, stream>>>(
        kT, vT, rT, x, lnum, lden, td, tf, yT, out);

    gemm_out<<<dim3(8, 32), 256, 0, stream>>>(yT, Wo, out);
}